// Round 7
// baseline (214.240 us; speedup 1.0000x reference)
//
#include <hip/hip_runtime.h>
#include <cfloat>

#define DIM 2048
#define NE  64

typedef _Float16 half8 __attribute__((ext_vector_type(8)));
typedef float    f32x4 __attribute__((ext_vector_type(4)));

struct Split { _Float16 hi, lo; };
template <int N> struct IC { static constexpr int v = N; };

// Split fp32 into fp16 hi + fp16 lo where x ≈ hi + lo/2048.
// hi clamped to 0 below fp16-min-normal so no denormal reaches the MFMA.
__device__ __forceinline__ Split split_f32(float x) {
    Split r;
    float h32;
    if (__builtin_fabsf(x) >= 6.103515625e-05f) {
        r.hi = (_Float16)x;          // v_cvt_f16_f32 (RTN)
        h32  = (float)r.hi;
    } else {
        r.hi = (_Float16)0.0f; h32 = 0.0f;
    }
    r.lo = (_Float16)((x - h32) * 2048.0f);
    return r;
}

// Pre-kernel: split W [64][2048] into fragment-ordered fp16 hi/lo in ws.
// hi element index: (sg*4 + nt)*64 + lane ; lo at +16384 (half8 units).
// Lane l of chunk (sg,nt) holds W[nt*16 + (l&15)][sg*32 + (l>>4)*8 + 0..7].
__global__ void wsplit_kernel(const float* __restrict__ W, _Float16* __restrict__ wsb) {
    int t    = blockIdx.x * 256 + threadIdx.x;   // 0..16383
    int lane = t & 63;
    int nt   = (t >> 6) & 3;
    int sg   = t >> 8;                           // k32-step 0..63
    int e    = nt * 16 + (lane & 15);
    int k    = sg * 32 + (lane >> 4) * 8;
    const float* wp = W + (size_t)e * DIM + k;
    half8 hi, lo;
    #pragma unroll
    for (int j = 0; j < 8; ++j) {
        Split s = split_f32(wp[j]);
        hi[j] = s.hi; lo[j] = s.lo;
    }
    ((half8*)wsb)[(size_t)((sg * 4 + nt) * 64 + lane)]         = hi;
    ((half8*)wsb)[(size_t)(16384 + (sg * 4 + nt) * 64 + lane)] = lo;
}

// Main (r7): identical work decomposition to r6 — 256 blocks x 512 thr
// (8 waves), block = 64 tokens, wave = K-eighth x 4 m-tiles (B reuse 4x,
// traffic-minimal: ~1 MB per CU). ONE change: the K-loop is expanded via a
// constexpr-index lambda so every local-array subscript (A ring slots, B
// buffers, accumulators) is a compile-time literal. Previous rounds indexed
// the rings with loop-derived cur/nxt/s%3 inside a body the compiler did not
// fully unroll -> rings lived in SCRATCH (rule: runtime-indexed ext_vector
// arrays go to local memory). Symptoms matched: VGPR_Count 32-48 (impossibly
// low), ~65 us of stall with all pipes idle, no HBM-level scratch traffic
// (scratch working set ~100 KB/CU stays L2-resident).
template <bool USE_WS>
__launch_bounds__(512, 2)
__global__ void gate_mfma_kernel(const float* __restrict__ x,
                                 const float* __restrict__ W,
                                 const float* __restrict__ b,
                                 float* __restrict__ out,
                                 const _Float16* __restrict__ wsb)
{
    __shared__ float sgrid[8][64][68];   // [k-eighth][token][expert], padded — 139 KB

    const int tid  = threadIdx.x;
    const int lane = tid & 63;
    const int wave = tid >> 6;           // k-eighth 0..7
    const int tokb = blockIdx.x * 64;

    const float* aptr = x + (size_t)(tokb + (lane & 15)) * DIM + wave * 256 + (lane >> 4) * 8;
    const half8* wb   = (const half8*)wsb;
    // half8 index for (s, nt): wave*2048 + s*256 + nt*64 + lane  (sg = wave*8+s)
    const int bbase = wave * 2048 + lane;

    f32x4 acch[4][4], accc[4][4];        // [m][nt] — always literal-indexed
    #pragma unroll
    for (int m = 0; m < 4; ++m)
        #pragma unroll
        for (int nt = 0; nt < 4; ++nt) {
            acch[m][nt] = (f32x4){0.f, 0.f, 0.f, 0.f};
            accc[m][nt] = (f32x4){0.f, 0.f, 0.f, 0.f};
        }

    half8 Bh[4], Bl[4];                  // single-buffered B
    f32x4 A0[2][4], A1[2][4];            // [slot][m], 1-ahead A double buffer

    // ---- preload: A step 0 (slot 0); B step 0 ----
    #pragma unroll
    for (int m = 0; m < 4; ++m) {
        const float* ap = aptr + (size_t)m * 16 * DIM;
        A0[0][m] = *(const f32x4*)(ap);
        A1[0][m] = *(const f32x4*)(ap + 4);
    }
    if (USE_WS) {
        #pragma unroll
        for (int nt = 0; nt < 4; ++nt) {
            Bh[nt] = wb[bbase + nt * 64];
            Bl[nt] = wb[16384 + bbase + nt * 64];
        }
    }

    // ---- K-loop: 8 steps, all ring indices compile-time ----
    auto step = [&](auto SC) {
        constexpr int s   = decltype(SC)::v;
        constexpr int cur = s & 1;
        constexpr int nxt = cur ^ 1;

        // issue next A (1 ahead) into the other slot — literal index
        if constexpr (s + 1 < 8) {
            #pragma unroll
            for (int m = 0; m < 4; ++m) {
                const float* ap = aptr + (size_t)m * 16 * DIM + (s + 1) * 32;
                A0[nxt][m] = *(const f32x4*)(ap);
                A1[nxt][m] = *(const f32x4*)(ap + 4);
            }
        }

        if constexpr (USE_WS) {
            // per m-tile: split (short-lived frags) + 12 MFMAs
            #pragma unroll
            for (int m = 0; m < 4; ++m) {
                half8 Ah, Al;
                #pragma unroll
                for (int j = 0; j < 4; ++j) {
                    Split s0 = split_f32(A0[cur][m][j]);
                    Ah[j] = s0.hi; Al[j] = s0.lo;
                    Split s1 = split_f32(A1[cur][m][j]);
                    Ah[4 + j] = s1.hi; Al[4 + j] = s1.lo;
                }
                #pragma unroll
                for (int nt = 0; nt < 4; ++nt) {
                    acch[m][nt] = __builtin_amdgcn_mfma_f32_16x16x32_f16(Ah, Bh[nt], acch[m][nt], 0, 0, 0);
                    accc[m][nt] = __builtin_amdgcn_mfma_f32_16x16x32_f16(Al, Bh[nt], accc[m][nt], 0, 0, 0);
                    accc[m][nt] = __builtin_amdgcn_mfma_f32_16x16x32_f16(Ah, Bl[nt], accc[m][nt], 0, 0, 0);
                }
            }
            // reload B for next step (WAR after MFMAs; hides under next A-split)
            if constexpr (s + 1 < 8) {
                #pragma unroll
                for (int nt = 0; nt < 4; ++nt) {
                    Bh[nt] = wb[bbase + (s + 1) * 256 + nt * 64];
                    Bl[nt] = wb[16384 + bbase + (s + 1) * 256 + nt * 64];
                }
            }
        } else {
            // fallback (never taken in bench): split B on demand from raw W
            constexpr int sg_base = 0;
            const int sg = wave * 8 + s + sg_base;
            #pragma unroll
            for (int nt = 0; nt < 4; ++nt) {
                half8 Bhc, Blc;
                const float* wp = W + (size_t)(nt * 16 + (lane & 15)) * DIM
                                    + sg * 32 + (lane >> 4) * 8;
                #pragma unroll
                for (int j = 0; j < 8; ++j) {
                    Split sp = split_f32(wp[j]);
                    Bhc[j] = sp.hi; Blc[j] = sp.lo;
                }
                #pragma unroll
                for (int m = 0; m < 4; ++m) {
                    half8 Ah, Al;
                    #pragma unroll
                    for (int j = 0; j < 4; ++j) {
                        Split s0 = split_f32(A0[cur][m][j]);
                        Ah[j] = s0.hi; Al[j] = s0.lo;
                        Split s1 = split_f32(A1[cur][m][j]);
                        Ah[4 + j] = s1.hi; Al[4 + j] = s1.lo;
                    }
                    acch[m][nt] = __builtin_amdgcn_mfma_f32_16x16x32_f16(Ah, Bhc, acch[m][nt], 0, 0, 0);
                    accc[m][nt] = __builtin_amdgcn_mfma_f32_16x16x32_f16(Al, Bhc, accc[m][nt], 0, 0, 0);
                    accc[m][nt] = __builtin_amdgcn_mfma_f32_16x16x32_f16(Ah, Blc, accc[m][nt], 0, 0, 0);
                }
            }
        }
    };
    step(IC<0>{}); step(IC<1>{}); step(IC<2>{}); step(IC<3>{});
    step(IC<4>{}); step(IC<5>{}); step(IC<6>{}); step(IC<7>{});

    // ---- partial scores to LDS: D row=(lane>>4)*4+r (token), col=lane&15 (expert) ----
    #pragma unroll
    for (int m = 0; m < 4; ++m)
        #pragma unroll
        for (int nt = 0; nt < 4; ++nt)
            #pragma unroll
            for (int r = 0; r < 4; ++r) {
                int tl = m * 16 + (lane >> 4) * 4 + r;
                int e  = nt * 16 + (lane & 15);
                sgrid[wave][tl][e] = acch[m][nt][r] + accc[m][nt][r] * (1.0f / 2048.0f);
            }
    __syncthreads();

    // ---- per-token top-2 + renormalized softmax (proven epilogue) ----
    // 8 waves x 8 tokens each = 64 tokens.
    const float bias = b[lane];
    #pragma unroll
    for (int tt = 0; tt < 8; ++tt) {
        const int t = wave * 8 + tt;
        float sv = bias;
        #pragma unroll
        for (int q = 0; q < 8; ++q) sv += sgrid[q][t][lane];

        float v = sv; int i = lane;
        #pragma unroll
        for (int off = 32; off > 0; off >>= 1) {
            float ov = __shfl_xor(v, off, 64);
            int   oi = __shfl_xor(i, off, 64);
            if (ov > v || (ov == v && oi < i)) { v = ov; i = oi; }
        }
        const float m1 = v; const int i1 = i;

        float s2 = (lane == i1) ? -FLT_MAX : sv;
        v = s2; i = lane;
        #pragma unroll
        for (int off = 32; off > 0; off >>= 1) {
            float ov = __shfl_xor(v, off, 64);
            int   oi = __shfl_xor(i, off, 64);
            if (ov > v || (ov == v && oi < i)) { v = ov; i = oi; }
        }
        const float m2 = v; const int i2 = i;

        const float e_  = __expf(m2 - m1);
        const float inv = 1.f / (1.f + e_);
        const float outv = (lane == i1) ? inv : ((lane == i2) ? e_ * inv : 0.f);
        out[(size_t)(tokb + t) * NE + lane] = outv;
    }
}

extern "C" void kernel_launch(void* const* d_in, const int* in_sizes, int n_in,
                              void* d_out, int out_size, void* d_ws, size_t ws_size,
                              hipStream_t stream) {
    const float* x = (const float*)d_in[0];
    const float* W = (const float*)d_in[1];
    const float* b = (const float*)d_in[2];
    float* out = (float*)d_out;

    const int n_tokens = in_sizes[0] / DIM;      // 16384
    dim3 grid(n_tokens / 64);                    // 256 blocks (1 per CU)
    dim3 block(512);                             // 8 waves

    // The 512 MB workspace re-poison fills (~154 µs/iter) are UNCONDITIONAL
    // (measured r4), so the 512 KB split-W fast path costs nothing extra.
    if (ws_size >= 524288) {
        wsplit_kernel<<<dim3(64), dim3(256), 0, stream>>>(W, (_Float16*)d_ws);
        gate_mfma_kernel<true><<<grid, block, 0, stream>>>(x, W, b, out, (const _Float16*)d_ws);
    } else {
        gate_mfma_kernel<false><<<grid, block, 0, stream>>>(x, W, b, out, nullptr);
    }
}

// Round 8
// 206.915 us; speedup vs baseline: 1.0354x; 1.0354x over previous
//
#include <hip/hip_runtime.h>
#include <cfloat>

#define DIM 2048
#define NE  64

typedef _Float16 half8 __attribute__((ext_vector_type(8)));
typedef float    f32x4 __attribute__((ext_vector_type(4)));

struct Split { _Float16 hi, lo; };

// Split fp32 into fp16 hi + fp16 lo where x ≈ hi + lo/2048.
// hi clamped to 0 below fp16-min-normal so no denormal reaches the MFMA.
__device__ __forceinline__ Split split_f32(float x) {
    Split r;
    float h32;
    if (__builtin_fabsf(x) >= 6.103515625e-05f) {
        r.hi = (_Float16)x;          // v_cvt_f16_f32 (RTN)
        h32  = (float)r.hi;
    } else {
        r.hi = (_Float16)0.0f; h32 = 0.0f;
    }
    r.lo = (_Float16)((x - h32) * 2048.0f);
    return r;
}

// Pre-kernel: split W [64][2048] into fragment-ordered fp16 hi/lo in ws.
// hi element index: (sg*4 + nt)*64 + lane ; lo at +16384 (half8 units).
// Lane l of chunk (sg,nt) holds W[nt*16 + (l&15)][sg*32 + (l>>4)*8 + 0..7].
__global__ void wsplit_kernel(const float* __restrict__ W, _Float16* __restrict__ wsb) {
    int t    = blockIdx.x * 256 + threadIdx.x;   // 0..16383
    int lane = t & 63;
    int nt   = (t >> 6) & 3;
    int sg   = t >> 8;                           // k32-step 0..63
    int e    = nt * 16 + (lane & 15);
    int k    = sg * 32 + (lane >> 4) * 8;
    const float* wp = W + (size_t)e * DIM + k;
    half8 hi, lo;
    #pragma unroll
    for (int j = 0; j < 8; ++j) {
        Split s = split_f32(wp[j]);
        hi[j] = s.hi; lo[j] = s.lo;
    }
    ((half8*)wsb)[(size_t)((sg * 4 + nt) * 64 + lane)]         = hi;
    ((half8*)wsb)[(size_t)(16384 + (sg * 4 + nt) * 64 + lane)] = lo;
}

// Main (r8): LEAN register-pressure rebuild.
// Diagnosis across r0-r7: VGPR_Count 32-48 for kernels with 120-250 VGPRs of
// declared pipeline state => the A/B buffers have been in SCRATCH all along
// (runtime-indexed arrays + over-cap pressure); every structural change was
// rearranging scratch traffic, hence the structure-independent ~75 us floor.
// Fix discipline: K-loop body holds ONLY named scalars (no arrays -> nothing
// to demote), acc[2][4] literal-indexed, peak live ~140 VGPR << 256 cap.
// Geometry: 512 blocks x 512 thr (8 waves), block = 32 tokens (m-reuse 2x:
// B traffic 268 MB), wave = K-eighth. LDS 69.6 KB -> 2 blocks/CU.
template <bool USE_WS>
__launch_bounds__(512, 2)
__global__ void gate_mfma_kernel(const float* __restrict__ x,
                                 const float* __restrict__ W,
                                 const float* __restrict__ b,
                                 float* __restrict__ out,
                                 const _Float16* __restrict__ wsb)
{
    __shared__ float sgrid[8][32][68];   // [k-eighth][token][expert] — 69.6 KB

    const int tid  = threadIdx.x;
    const int lane = tid & 63;
    const int wave = tid >> 6;           // k-eighth 0..7
    const int tokb = blockIdx.x * 32;

    const float* aptr0 = x + (size_t)(tokb + (lane & 15)) * DIM + wave * 256 + (lane >> 4) * 8;
    const float* aptr1 = aptr0 + (size_t)16 * DIM;
    const half8* wb    = (const half8*)wsb;
    int boff = wave * 2048 + lane;       // half8 index of (sg=wave*8, nt=0)

    // fallback-path W pointers (dead code when USE_WS)
    const float* wp0 = W + (size_t)( 0 + (lane & 15)) * DIM + wave * 256 + (lane >> 4) * 8;
    const float* wp1 = wp0 + (size_t)16 * DIM;
    const float* wp2 = wp1 + (size_t)16 * DIM;
    const float* wp3 = wp2 + (size_t)16 * DIM;

    f32x4 acch[2][4], accc[2][4];        // literal-indexed everywhere
    #pragma unroll
    for (int m = 0; m < 2; ++m)
        #pragma unroll
        for (int nt = 0; nt < 4; ++nt) {
            acch[m][nt] = (f32x4){0.f, 0.f, 0.f, 0.f};
            accc[m][nt] = (f32x4){0.f, 0.f, 0.f, 0.f};
        }

    for (int s = 0; s < 8; ++s) {
        // ---- A loads: 2 m-tiles x 8 floats, named scalars ----
        f32x4 a00 = *(const f32x4*)(aptr0);
        f32x4 a01 = *(const f32x4*)(aptr0 + 4);
        f32x4 a10 = *(const f32x4*)(aptr1);
        f32x4 a11 = *(const f32x4*)(aptr1 + 4);

        // ---- B: 4 expert-tiles, named scalars ----
        half8 bh0, bh1, bh2, bh3, bl0, bl1, bl2, bl3;
        if constexpr (USE_WS) {
            bh0 = wb[boff];           bh1 = wb[boff + 64];
            bh2 = wb[boff + 128];     bh3 = wb[boff + 192];
            bl0 = wb[16384 + boff];       bl1 = wb[16384 + boff + 64];
            bl2 = wb[16384 + boff + 128]; bl3 = wb[16384 + boff + 192];
        } else {
            f32x4 w00 = *(const f32x4*)(wp0), w01 = *(const f32x4*)(wp0 + 4);
            f32x4 w10 = *(const f32x4*)(wp1), w11 = *(const f32x4*)(wp1 + 4);
            f32x4 w20 = *(const f32x4*)(wp2), w21 = *(const f32x4*)(wp2 + 4);
            f32x4 w30 = *(const f32x4*)(wp3), w31 = *(const f32x4*)(wp3 + 4);
            #pragma unroll
            for (int j = 0; j < 4; ++j) {
                Split t0 = split_f32(w00[j]); bh0[j] = t0.hi; bl0[j] = t0.lo;
                Split t1 = split_f32(w01[j]); bh0[4+j] = t1.hi; bl0[4+j] = t1.lo;
                Split t2 = split_f32(w10[j]); bh1[j] = t2.hi; bl1[j] = t2.lo;
                Split t3 = split_f32(w11[j]); bh1[4+j] = t3.hi; bl1[4+j] = t3.lo;
                Split t4 = split_f32(w20[j]); bh2[j] = t4.hi; bl2[j] = t4.lo;
                Split t5 = split_f32(w21[j]); bh2[4+j] = t5.hi; bl2[4+j] = t5.lo;
                Split t6 = split_f32(w30[j]); bh3[j] = t6.hi; bl3[j] = t6.lo;
                Split t7 = split_f32(w31[j]); bh3[4+j] = t7.hi; bl3[4+j] = t7.lo;
            }
            wp0 += 32; wp1 += 32; wp2 += 32; wp3 += 32;
        }

        // ---- split A, named scalars ----
        half8 Ah0, Al0, Ah1, Al1;
        #pragma unroll
        for (int j = 0; j < 4; ++j) {
            Split s0 = split_f32(a00[j]); Ah0[j]     = s0.hi; Al0[j]     = s0.lo;
            Split s1 = split_f32(a01[j]); Ah0[4 + j] = s1.hi; Al0[4 + j] = s1.lo;
            Split s2 = split_f32(a10[j]); Ah1[j]     = s2.hi; Al1[j]     = s2.lo;
            Split s3 = split_f32(a11[j]); Ah1[4 + j] = s3.hi; Al1[4 + j] = s3.lo;
        }

        // ---- 24 MFMAs: each B fragment feeds both m-tiles ----
#define MM(m, nt, AH, AL, BH, BL) \
        acch[m][nt] = __builtin_amdgcn_mfma_f32_16x16x32_f16(AH, BH, acch[m][nt], 0, 0, 0); \
        accc[m][nt] = __builtin_amdgcn_mfma_f32_16x16x32_f16(AL, BH, accc[m][nt], 0, 0, 0); \
        accc[m][nt] = __builtin_amdgcn_mfma_f32_16x16x32_f16(AH, BL, accc[m][nt], 0, 0, 0);
        MM(0, 0, Ah0, Al0, bh0, bl0)
        MM(1, 0, Ah1, Al1, bh0, bl0)
        MM(0, 1, Ah0, Al0, bh1, bl1)
        MM(1, 1, Ah1, Al1, bh1, bl1)
        MM(0, 2, Ah0, Al0, bh2, bl2)
        MM(1, 2, Ah1, Al1, bh2, bl2)
        MM(0, 3, Ah0, Al0, bh3, bl3)
        MM(1, 3, Ah1, Al1, bh3, bl3)
#undef MM

        aptr0 += 32; aptr1 += 32; boff += 256;
    }

    // ---- partial scores to LDS: D row=(lane>>4)*4+r (token), col=lane&15 (expert) ----
    #pragma unroll
    for (int m = 0; m < 2; ++m)
        #pragma unroll
        for (int nt = 0; nt < 4; ++nt)
            #pragma unroll
            for (int r = 0; r < 4; ++r) {
                int tl = m * 16 + (lane >> 4) * 4 + r;
                int e  = nt * 16 + (lane & 15);
                sgrid[wave][tl][e] = acch[m][nt][r] + accc[m][nt][r] * (1.0f / 2048.0f);
            }
    __syncthreads();

    // ---- per-token top-2 + renormalized softmax (proven epilogue) ----
    // 8 waves x 4 tokens each = 32 tokens.
    const float bias = b[lane];
    #pragma unroll
    for (int tt = 0; tt < 4; ++tt) {
        const int t = wave * 4 + tt;
        float sv = bias;
        #pragma unroll
        for (int q = 0; q < 8; ++q) sv += sgrid[q][t][lane];

        float v = sv; int i = lane;
        #pragma unroll
        for (int off = 32; off > 0; off >>= 1) {
            float ov = __shfl_xor(v, off, 64);
            int   oi = __shfl_xor(i, off, 64);
            if (ov > v || (ov == v && oi < i)) { v = ov; i = oi; }
        }
        const float m1 = v; const int i1 = i;

        float s2 = (lane == i1) ? -FLT_MAX : sv;
        v = s2; i = lane;
        #pragma unroll
        for (int off = 32; off > 0; off >>= 1) {
            float ov = __shfl_xor(v, off, 64);
            int   oi = __shfl_xor(i, off, 64);
            if (ov > v || (ov == v && oi < i)) { v = ov; i = oi; }
        }
        const float m2 = v; const int i2 = i;

        const float e_  = __expf(m2 - m1);
        const float inv = 1.f / (1.f + e_);
        const float outv = (lane == i1) ? inv : ((lane == i2) ? e_ * inv : 0.f);
        out[(size_t)(tokb + t) * NE + lane] = outv;
    }
}

extern "C" void kernel_launch(void* const* d_in, const int* in_sizes, int n_in,
                              void* d_out, int out_size, void* d_ws, size_t ws_size,
                              hipStream_t stream) {
    const float* x = (const float*)d_in[0];
    const float* W = (const float*)d_in[1];
    const float* b = (const float*)d_in[2];
    float* out = (float*)d_out;

    const int n_tokens = in_sizes[0] / DIM;      // 16384
    dim3 grid(n_tokens / 32);                    // 512 blocks (2 per CU)
    dim3 block(512);                             // 8 waves

    // The 512 MB workspace re-poison fills (~154 µs/iter) are UNCONDITIONAL
    // (measured r4), so the 512 KB split-W fast path costs nothing extra.
    if (ws_size >= 524288) {
        wsplit_kernel<<<dim3(64), dim3(256), 0, stream>>>(W, (_Float16*)d_ws);
        gate_mfma_kernel<true><<<grid, block, 0, stream>>>(x, W, b, out, (const _Float16*)d_ws);
    } else {
        gate_mfma_kernel<false><<<grid, block, 0, stream>>>(x, W, b, out, nullptr);
    }
}